// Round 16
// baseline (142.046 us; speedup 1.0000x reference)
//
#include <hip/hip_runtime.h>

#define N_NODES 50000
#define N_EDGES 800000
#define IN_DIM 128
#define HID 64
#define N_GRAPHS 256

#define E_PER_BLK 4000
#define F_BLOCKS (N_EDGES / E_PER_BLK)      // 200
#define NBKT ((N_NODES + 255) / 256)        // 196 coarse buckets of 256 nodes
#define CNT_N (NBKT * F_BLOCKS)             // 39200
#define SCB ((CNT_N + 255) / 256)           // 154
#define NTILES (N_NODES / 4)                // 12500 (exact)
#define MTILES (N_NODES / 16)               // 3125 mfma node-tiles (exact)
#define DCNT_N (64 * NBKT)                  // 12544 degree-hist entries
#define DSCB ((DCNT_N + 255) / 256)         // 49

// NOTES:
// (r3-4) __launch_bounds__ min-waves arg => VGPR cap halved, ~1.1 GB scratch spill. Plain bounds.
// (r5)   single-block scan = 125 us one-CU latency; hierarchical scans only.
// (r7)   atomic-cursor CSR fill (800K device atomics) -> LDS counting sort.
// (r8)   big per-lane W arrays -> compiler caps ~85 VGPR and REMATERIALIZES weight loads.
// (r11)  values live ACROSS __syncthreads -> VGPR 132, occupancy 10%, 2x regression.
// (r13)  mlp -> MFMA 16x16x32 bf16 (fragment-ordered W in LDS), verified layouts.
// (r14)  gather fused into MFMA mlp (lane owns its row's feature chunks).
// (r15)  degree-sorted node permutation: wave-max deg ~= mean (-40% gather iters), -7.6 us.
// (r16)  fused kernel was wave-starved (782 blocks x 4 waves = 12 waves/CU). Now 2 waves
//        co-own each tile (split neighbor range, bf16 partials in padded LDS), both waves
//        do half the MFMA columns. 512-thr blocks, 4 tiles/block, ~24 waves/CU.

__device__ __forceinline__ float bf2f(unsigned short v) {
  return __uint_as_float(((unsigned int)v) << 16);
}
__device__ __forceinline__ unsigned short f2bf(float f) {
  unsigned int u = __float_as_uint(f);
  return (unsigned short)((u + 0x7fffu + ((u >> 16) & 1u)) >> 16);  // RNE
}

typedef __attribute__((ext_vector_type(8))) short bf16x8;
typedef __attribute__((ext_vector_type(4))) float f32x4;

// ---- F1: per-(block, coarse-bucket) histogram of dst ----
__global__ __launch_bounds__(256) void part_hist_kernel(const int* __restrict__ dst,
                                                        int* __restrict__ cnt) {
  __shared__ int h[NBKT];
  const int t = threadIdx.x;
  for (int k = t; k < NBKT; k += 256) h[k] = 0;
  __syncthreads();
  const int base = blockIdx.x * E_PER_BLK;
  for (int i = t; i < E_PER_BLK; i += 256) atomicAdd(&h[dst[base + i] >> 8], 1);
  __syncthreads();
  for (int k = t; k < NBKT; k += 256) cnt[k * F_BLOCKS + blockIdx.x] = h[k];
}

// ---- generic hierarchical exclusive scan (block prefix applied at use site) ----
__global__ __launch_bounds__(256) void scan1g_kernel(const int* __restrict__ in,
                                                     int* __restrict__ ex,
                                                     int* __restrict__ bsum, int n) {
  __shared__ int s[256];
  const int t = threadIdx.x;
  const int i = blockIdx.x * 256 + t;
  int v = (i < n) ? in[i] : 0;
  s[t] = v;
  __syncthreads();
#pragma unroll
  for (int ofs = 1; ofs < 256; ofs <<= 1) {
    int u = (t >= ofs) ? s[t - ofs] : 0;
    __syncthreads();
    s[t] += u;
    __syncthreads();
  }
  if (i < n) ex[i] = s[t] - v;
  if (t == 255) bsum[blockIdx.x] = s[255];
}

__global__ __launch_bounds__(256) void scan2g_kernel(const int* __restrict__ bsum,
                                                     int* __restrict__ bpref, int nb) {
  __shared__ int s[256];
  const int t = threadIdx.x;
  int v = (t < nb) ? bsum[t] : 0;
  s[t] = v;
  __syncthreads();
#pragma unroll
  for (int ofs = 1; ofs < 256; ofs <<= 1) {
    int u = (t >= ofs) ? s[t - ofs] : 0;
    __syncthreads();
    s[t] += u;
    __syncthreads();
  }
  if (t < nb) bpref[t] = s[t] - v;
}

// ---- F3: partition edges into coarse-bucket order (LDS cursors; bpref applied inline) ----
__global__ __launch_bounds__(256) void part_scatter_kernel(const int* __restrict__ src,
                                                           const int* __restrict__ dst,
                                                           const int* __restrict__ cex,
                                                           const int* __restrict__ bpref,
                                                           int* __restrict__ psrc,
                                                           int* __restrict__ pdst) {
  __shared__ int cur[NBKT];
  const int t = threadIdx.x;
  for (int k = t; k < NBKT; k += 256) {
    const int i = k * F_BLOCKS + blockIdx.x;
    cur[k] = cex[i] + bpref[i >> 8];
  }
  __syncthreads();
  const int base = blockIdx.x * E_PER_BLK;
  for (int i = t; i < E_PER_BLK; i += 256) {
    int d = dst[base + i], s = src[base + i];
    int p = atomicAdd(&cur[d >> 8], 1);
    pdst[p] = d;
    psrc[p] = s;
  }
}

// ---- F4: per-bucket counting sort -> csr + off; degree histogram folded in ----
__global__ __launch_bounds__(256) void bucket_sort_kernel(const int* __restrict__ psrc,
                                                          const int* __restrict__ pdst,
                                                          const int* __restrict__ cex,
                                                          const int* __restrict__ bpref,
                                                          int* __restrict__ csr,
                                                          int* __restrict__ off,
                                                          int* __restrict__ dcnt) {
  const int k = blockIdx.x;
  const int t = threadIdx.x;
  const int i0 = k * F_BLOCKS;
  const int b0 = cex[i0] + bpref[i0 >> 8];
  int b1 = N_EDGES;
  if (k != NBKT - 1) {
    const int i1 = (k + 1) * F_BLOCKS;
    b1 = cex[i1] + bpref[i1 >> 8];
  }
  __shared__ int cnt[256];
  __shared__ int s[256];
  __shared__ int cur[256];
  __shared__ int dhist[64];
  cnt[t] = 0;
  if (t < 64) dhist[t] = 0;
  __syncthreads();
  for (int i = b0 + t; i < b1; i += 256) atomicAdd(&cnt[pdst[i] & 255], 1);
  __syncthreads();
  int v = cnt[t];
  s[t] = v;
  __syncthreads();
#pragma unroll
  for (int ofs = 1; ofs < 256; ofs <<= 1) {
    int u = (t >= ofs) ? s[t - ofs] : 0;
    __syncthreads();
    s[t] += u;
    __syncthreads();
  }
  const int node = (k << 8) + t;
  const int start = b0 + s[t] - v;
  cur[t] = start;
  if (node < N_NODES) {
    off[node] = start;
    atomicAdd(&dhist[(v < 63) ? v : 63], 1);
  }
  if (k == NBKT - 1 && t == 0) off[N_NODES] = N_EDGES;
  __syncthreads();
  if (t < 64) dcnt[t * NBKT + k] = dhist[t];
  for (int i = b0 + t; i < b1; i += 256) {
    int d = pdst[i];
    int p = atomicAdd(&cur[d & 255], 1);
    csr[p] = psrc[i];
  }
}

// ---- F5: scatter nodes into degree-sorted permutation ----
__global__ __launch_bounds__(256) void perm_scatter_kernel(const int* __restrict__ off,
                                                           const int* __restrict__ dex,
                                                           const int* __restrict__ dbpref,
                                                           int* __restrict__ perm) {
  __shared__ int cur[64];
  const int k = blockIdx.x, t = threadIdx.x;
  if (t < 64) {
    const int i = t * NBKT + k;
    cur[t] = dex[i] + dbpref[i >> 8];
  }
  __syncthreads();
  const int node = (k << 8) + t;
  if (node < N_NODES) {
    int d = off[node + 1] - off[node];
    d = (d < 63) ? d : 63;
    int pos = atomicAdd(&cur[d], 1);
    perm[pos] = node;
  }
}

// ---- proj: h = relu(x @ Wp + bp). Split-K wave pairs, 4-node tiles, bf16 out ----
__global__ __launch_bounds__(256) void proj_kernel(
    const float* __restrict__ x, const float* __restrict__ Wp,
    const float* __restrict__ bp, unsigned short* __restrict__ h) {
  __shared__ __align__(16) float sX[2][2][4][64];     // [pair][khalf][t][k]
  __shared__ __align__(16) float sPart[2][2][4][64];  // [pair][buf][t][j]
  const int wave = threadIdx.x >> 6, lane = threadIdx.x & 63;
  const int pair = wave >> 1, khalf = wave & 1;
  float w[64];
#pragma unroll
  for (int k = 0; k < 64; ++k) w[k] = Wp[(khalf * 64 + k) * HID + lane];  // coalesced
  const float bias = bp[lane];
  const int pv = blockIdx.x * 2 + pair;
  const int np = gridDim.x * 2;
  const int iters = (NTILES - blockIdx.x * 2 + np - 1) / np;  // block-uniform
  for (int it = 0; it < iters; ++it) {
    const int tile = pv + it * np;
    const bool act = (tile < NTILES);
    const int n0 = tile * 4;
    const int buf = it & 1;
    if (act) {
#pragma unroll
      for (int t = 0; t < 4; ++t)
        sX[pair][khalf][t][lane] = x[(n0 + t) * IN_DIM + khalf * 64 + lane];
    }
    float p[4];
#pragma unroll
    for (int t = 0; t < 4; ++t) {
      float a0 = khalf ? 0.f : bias, a1 = 0.f, a2 = 0.f, a3 = 0.f;
#pragma unroll
      for (int k = 0; k < 64; k += 4) {
        float4 v = *(const float4*)&sX[pair][khalf][t][k];  // same-addr broadcast
        a0 = fmaf(v.x, w[k + 0], a0);
        a1 = fmaf(v.y, w[k + 1], a1);
        a2 = fmaf(v.z, w[k + 2], a2);
        a3 = fmaf(v.w, w[k + 3], a3);
      }
      p[t] = (a0 + a1) + (a2 + a3);
    }
    if (act && khalf) {
#pragma unroll
      for (int t = 0; t < 4; ++t) sPart[pair][buf][t][lane] = p[t];
    }
    __syncthreads();
    if (act && !khalf) {
#pragma unroll
      for (int t = 0; t < 4; ++t)
        h[(n0 + t) * HID + lane] = f2bf(fmaxf(p[t] + sPart[pair][buf][t][lane], 0.0f));
    }
  }
}

// ---- fused GIN layer (MFMA, degree-sorted, 2 waves per tile) ----
// Wave pair (half=0/1) splits each row's neighbor range; partials exchanged via LDS
// (bf16, rows padded to 72 to spread banks); both waves build the full A-fragment and
// each computes 2 of 4 N-columns in both MFMA stages. 4 tiles per 512-thread block.
__global__ __launch_bounds__(512) void gin_fused_mfma_kernel(
    const unsigned short* __restrict__ h_in, const int* __restrict__ off,
    const int* __restrict__ csr, const int* __restrict__ perm,
    const float* __restrict__ W1, const float* __restrict__ b1,
    const float* __restrict__ W2, const float* __restrict__ b2,
    unsigned short* __restrict__ h_out) {
  __shared__ __align__(16) unsigned short sW1[4096];          // 8 KB, fragment-ordered
  __shared__ __align__(16) unsigned short sW2[4096];          // 8 KB
  __shared__ __align__(16) unsigned short sPar[2][4][16][72]; // 18 KB partials
  __shared__ __align__(16) unsigned short sT1[4][16][72];     // 9 KB stage-1 out
  __shared__ __align__(16) unsigned short sT2[4][16][72];     // 9 KB stage-2 out
  const int t = threadIdx.x;
  for (int i = t; i < 4096; i += 512) {
    const int k = i >> 6, j = i & 63;
    const int pos = (((j >> 4) * 2 + (k >> 5)) * 64 + ((k >> 3) & 3) * 16 + (j & 15)) * 8 + (k & 7);
    sW1[pos] = f2bf(W1[i]);
    sW2[pos] = f2bf(W2[i]);
  }
  __syncthreads();  // B0
  const int wave = t >> 6, lane = t & 63;
  const int pair = wave >> 1, half = wave & 1;
  const int row = lane & 15;   // A-row / D-col
  const int kgrp = lane >> 4;  // 0..3
  const int tile = blockIdx.x * 4 + pair;
  const bool act = (tile < MTILES);
  int n = 0, o0 = 0, deg = 0;
  if (act) {
    n = perm[(tile << 4) + row];
    o0 = off[n];
    deg = off[n + 1] - o0;
  }
  const int jbeg = half ? (deg + 1) >> 1 : 0;
  const int jend = half ? deg : (deg + 1) >> 1;
  const int cntw = jend - jbeg;
  int dm = cntw;  // wave-max over the 16 rows (only low 4 lane bits vary)
#pragma unroll
  for (int m = 1; m <= 8; m <<= 1) {
    int o = __shfl_xor(dm, m);
    dm = (o > dm) ? o : dm;
  }
  const uint4* __restrict__ hv = (const uint4*)h_in;  // 8 x 16B segments per row
  float ac0[8], ac1[8];
#pragma unroll
  for (int e = 0; e < 8; ++e) {
    ac0[e] = 0.0f;
    ac1[e] = 0.0f;
  }
  if (act && !half) {  // self term (eps = 0), counted once
    uint4 ua = hv[n * 8 + kgrp];
    uint4 ub = hv[n * 8 + 4 + kgrp];
    const unsigned int* pa = (const unsigned int*)&ua;
    const unsigned int* pb = (const unsigned int*)&ub;
#pragma unroll
    for (int e = 0; e < 4; ++e) {
      ac0[2 * e] = bf2f((unsigned short)(pa[e] & 0xffff));
      ac0[2 * e + 1] = bf2f((unsigned short)(pa[e] >> 16));
      ac1[2 * e] = bf2f((unsigned short)(pb[e] & 0xffff));
      ac1[2 * e + 1] = bf2f((unsigned short)(pb[e] >> 16));
    }
  }
  for (int j = 0; j < dm; j += 4) {  // branchless, 4-way unrolled
#pragma unroll
    for (int u = 0; u < 4; ++u) {
      const int jj = j + u;
      int pos = o0 + jbeg + ((jj < cntw) ? jj : 0);
      const int idx = csr[(pos < N_EDGES) ? pos : (N_EDGES - 1)];
      const float m = (jj < cntw) ? 1.0f : 0.0f;
      uint4 ua = hv[idx * 8 + kgrp];
      uint4 ub = hv[idx * 8 + 4 + kgrp];
      const unsigned int* pa = (const unsigned int*)&ua;
      const unsigned int* pb = (const unsigned int*)&ub;
#pragma unroll
      for (int e = 0; e < 4; ++e) {
        ac0[2 * e] = fmaf(m, bf2f((unsigned short)(pa[e] & 0xffff)), ac0[2 * e]);
        ac0[2 * e + 1] = fmaf(m, bf2f((unsigned short)(pa[e] >> 16)), ac0[2 * e + 1]);
        ac1[2 * e] = fmaf(m, bf2f((unsigned short)(pb[e] & 0xffff)), ac1[2 * e]);
        ac1[2 * e + 1] = fmaf(m, bf2f((unsigned short)(pb[e] >> 16)), ac1[2 * e + 1]);
      }
    }
  }
  // publish own partial (bf16)
  {
    bf16x8 p0, p1;
#pragma unroll
    for (int e = 0; e < 8; ++e) {
      p0[e] = (short)f2bf(ac0[e]);
      p1[e] = (short)f2bf(ac1[e]);
    }
    *(bf16x8*)&sPar[half][pair][row][kgrp * 8] = p0;
    *(bf16x8*)&sPar[half][pair][row][32 + kgrp * 8] = p1;
  }
  __syncthreads();  // B1
  // combine: add other wave's partial -> full agg; pack A-fragments
  bf16x8 a1[2];
  {
    bf16x8 q0 = *(const bf16x8*)&sPar[1 - half][pair][row][kgrp * 8];
    bf16x8 q1 = *(const bf16x8*)&sPar[1 - half][pair][row][32 + kgrp * 8];
#pragma unroll
    for (int e = 0; e < 8; ++e) {
      a1[0][e] = (short)f2bf(ac0[e] + bf2f((unsigned short)q0[e]));
      a1[1][e] = (short)f2bf(ac1[e] + bf2f((unsigned short)q1[e]));
    }
  }
  // stage 1: this wave's two N-columns
  f32x4 acc;
#pragma unroll
  for (int q = 0; q < 2; ++q) {
    const int nc = 2 * half + q;
    const float bb = b1[nc * 16 + row];
    acc = (f32x4){bb, bb, bb, bb};
#pragma unroll
    for (int ks = 0; ks < 2; ++ks) {
      bf16x8 bf = *(const bf16x8*)&sW1[((nc * 2 + ks) * 64 + lane) * 8];
      acc = __builtin_amdgcn_mfma_f32_16x16x32_bf16(a1[ks], bf, acc, 0, 0, 0);
    }
#pragma unroll
    for (int r = 0; r < 4; ++r)
      sT1[pair][kgrp * 4 + r][nc * 16 + row] = f2bf(fmaxf(acc[r], 0.0f));
  }
  __syncthreads();  // B2
  bf16x8 a2[2];
  a2[0] = *(const bf16x8*)&sT1[pair][row][kgrp * 8];
  a2[1] = *(const bf16x8*)&sT1[pair][row][32 + kgrp * 8];
#pragma unroll
  for (int q = 0; q < 2; ++q) {
    const int nc = 2 * half + q;
    const float bb = b2[nc * 16 + row];
    acc = (f32x4){bb, bb, bb, bb};
#pragma unroll
    for (int ks = 0; ks < 2; ++ks) {
      bf16x8 bf = *(const bf16x8*)&sW2[((nc * 2 + ks) * 64 + lane) * 8];
      acc = __builtin_amdgcn_mfma_f32_16x16x32_bf16(a2[ks], bf, acc, 0, 0, 0);
    }
#pragma unroll
    for (int r = 0; r < 4; ++r)
      sT2[pair][kgrp * 4 + r][nc * 16 + row] = f2bf(fmaxf(acc[r], 0.0f));
  }
  __syncthreads();  // B3
  if (act) {  // store: this wave covers 8 rows x 64 bf16 via uint4
    const int idx2 = half * 64 + lane;
    const int ri = idx2 >> 3, ch = idx2 & 7;
    const int nodeo = perm[(tile << 4) + ri];  // L1-hot reload
    uint4 v = *(const uint4*)&sT2[pair][ri][ch * 8];
    *(uint4*)&h_out[nodeo * HID + ch * 8] = v;
  }
}

// ------- pool: batch sorted -> one block per graph, binary-search range -------
__global__ __launch_bounds__(256) void pool_kernel(const unsigned short* __restrict__ h,
                                                   const int* __restrict__ batch,
                                                   float* __restrict__ out) {
  const int g = blockIdx.x;
  int lo = 0, hi = N_NODES;
  while (lo < hi) {
    int mid = (lo + hi) >> 1;
    if (batch[mid] < g) lo = mid + 1; else hi = mid;
  }
  const int s = lo;
  hi = N_NODES;
  while (lo < hi) {
    int mid = (lo + hi) >> 1;
    if (batch[mid] < g + 1) lo = mid + 1; else hi = mid;
  }
  const int e = lo;
  const int wave = threadIdx.x >> 6, lane = threadIdx.x & 63;
  float a0 = 0.f, a1 = 0.f, a2 = 0.f, a3 = 0.f;
  int n = s + wave;
  for (; n + 12 < e; n += 16) {
    a0 += bf2f(h[n * HID + lane]);
    a1 += bf2f(h[(n + 4) * HID + lane]);
    a2 += bf2f(h[(n + 8) * HID + lane]);
    a3 += bf2f(h[(n + 12) * HID + lane]);
  }
  for (; n < e; n += 4) a0 += bf2f(h[n * HID + lane]);
  __shared__ float red[4][HID];
  red[wave][lane] = ((a0 + a1) + (a2 + a3));
  __syncthreads();
  if (wave == 0) {
    float v = red[0][lane] + red[1][lane] + red[2][lane] + red[3][lane];
    float cnt = (float)(e - s);
    out[g * HID + lane] = v / fmaxf(cnt, 1.0f);
  }
}

extern "C" void kernel_launch(void* const* d_in, const int* in_sizes, int n_in,
                              void* d_out, int out_size, void* d_ws, size_t ws_size,
                              hipStream_t stream) {
  const float* x    = (const float*)d_in[0];
  const int*   edge = (const int*)d_in[1];
  const int*   batch= (const int*)d_in[2];
  const float* Wp   = (const float*)d_in[3];
  const float* bp   = (const float*)d_in[4];
  const float* W1_0 = (const float*)d_in[5];
  const float* b1_0 = (const float*)d_in[6];
  const float* W2_0 = (const float*)d_in[7];
  const float* b2_0 = (const float*)d_in[8];
  const float* W1_1 = (const float*)d_in[9];
  const float* b1_1 = (const float*)d_in[10];
  const float* W2_1 = (const float*)d_in[11];
  const float* b2_1 = (const float*)d_in[12];
  const int* src = edge;
  const int* dst = edge + N_EDGES;
  float* out = (float*)d_out;

  const size_t NB = (size_t)N_NODES * HID;
  unsigned short* hA = (unsigned short*)d_ws;  // NB bf16
  unsigned short* hB = hA + NB;                // NB bf16
  int* off     = (int*)(hB + NB);   // N_NODES+1
  int* cnt     = off + N_NODES + 1; // CNT_N
  int* cex     = cnt + CNT_N;       // CNT_N
  int* sbsum   = cex + CNT_N;       // SCB
  int* sbpref  = sbsum + SCB;       // SCB
  int* dcnt    = sbpref + SCB;      // DCNT_N
  int* dex     = dcnt + DCNT_N;     // DCNT_N
  int* dbsum   = dex + DCNT_N;      // DSCB
  int* dbpref  = dbsum + DSCB;      // DSCB
  int* perm    = dbpref + DSCB;     // N_NODES
  int* pdst    = perm + N_NODES;    // N_EDGES
  int* psrc    = pdst + N_EDGES;    // N_EDGES
  int* csr     = psrc + N_EDGES;    // N_EDGES

  dim3 b256(256), b512(512);

  // CSR build: counting sort, zero global atomics
  part_hist_kernel<<<F_BLOCKS, b256, 0, stream>>>(dst, cnt);
  scan1g_kernel<<<SCB, b256, 0, stream>>>(cnt, cex, sbsum, CNT_N);
  scan2g_kernel<<<1, b256, 0, stream>>>(sbsum, sbpref, SCB);
  part_scatter_kernel<<<F_BLOCKS, b256, 0, stream>>>(src, dst, cex, sbpref, psrc, pdst);
  bucket_sort_kernel<<<NBKT, b256, 0, stream>>>(psrc, pdst, cex, sbpref, csr, off, dcnt);

  // degree-sorted permutation
  scan1g_kernel<<<DSCB, b256, 0, stream>>>(dcnt, dex, dbsum, DCNT_N);
  scan2g_kernel<<<1, b256, 0, stream>>>(dbsum, dbpref, DSCB);
  perm_scatter_kernel<<<NBKT, b256, 0, stream>>>(off, dex, dbpref, perm);

  // h0 -> hA
  proj_kernel<<<2048, b256, 0, stream>>>(x, Wp, bp, hA);

  // fused layers: hA -> hB -> hA  (782 blocks x 4 tiles = 3128 tiles >= 3125)
  gin_fused_mfma_kernel<<<782, b512, 0, stream>>>(hA, off, csr, perm, W1_0, b1_0, W2_0, b2_0, hB);
  gin_fused_mfma_kernel<<<782, b512, 0, stream>>>(hB, off, csr, perm, W1_1, b1_1, W2_1, b2_1, hA);

  // pool
  pool_kernel<<<N_GRAPHS, b256, 0, stream>>>(hA, batch, out);
}

// Round 17
// 127.552 us; speedup vs baseline: 1.1136x; 1.1136x over previous
//
#include <hip/hip_runtime.h>

#define N_NODES 50000
#define N_EDGES 800000
#define IN_DIM 128
#define HID 64
#define N_GRAPHS 256

#define E_PER_BLK 4000
#define F_BLOCKS (N_EDGES / E_PER_BLK)      // 200
#define NBKT ((N_NODES + 255) / 256)        // 196 coarse buckets of 256 nodes
#define CNT_N (NBKT * F_BLOCKS)             // 39200
#define SCB ((CNT_N + 255) / 256)           // 154
#define MTILES (N_NODES / 16)               // 3125 mfma node-tiles (exact)
#define DCNT_N (64 * NBKT)                  // 12544 degree-hist entries
#define DSCB ((DCNT_N + 255) / 256)         // 49

// NOTES:
// (r3-4) __launch_bounds__ min-waves arg => VGPR cap halved, ~1.1 GB scratch spill. Plain bounds.
// (r5)   single-block scan = 125 us one-CU latency; hierarchical scans only.
// (r7)   atomic-cursor CSR fill (800K device atomics) -> LDS counting sort.
// (r8)   big per-lane W arrays -> compiler caps ~85 VGPR and REMATERIALIZES weight loads.
// (r11)  values live ACROSS __syncthreads -> VGPR 132, occupancy 10%, 2x regression.
// (r13)  mlp -> MFMA 16x16x32 bf16 (fragment-ordered W in LDS), verified layouts.
// (r14)  gather fused into MFMA mlp (lane owns its row's feature chunks).
// (r15)  degree-sorted node permutation (wave-max deg ~= mean), -7.6 us. BEST 133.2.
// (r16)  2-wave-per-tile split: barrier coupling + partial round-trip ate the occupancy
//        gain (+9 us). REVERTED. Rule: one wave per tile; no multi-wave cooperation here.
// (r17)  proj -> MFMA (K=128, 4 k-steps), same verified fragment scheme as mlp.

__device__ __forceinline__ float bf2f(unsigned short v) {
  return __uint_as_float(((unsigned int)v) << 16);
}
__device__ __forceinline__ unsigned short f2bf(float f) {
  unsigned int u = __float_as_uint(f);
  return (unsigned short)((u + 0x7fffu + ((u >> 16) & 1u)) >> 16);  // RNE
}

typedef __attribute__((ext_vector_type(8))) short bf16x8;
typedef __attribute__((ext_vector_type(4))) float f32x4;

// ---- F1: per-(block, coarse-bucket) histogram of dst ----
__global__ __launch_bounds__(256) void part_hist_kernel(const int* __restrict__ dst,
                                                        int* __restrict__ cnt) {
  __shared__ int h[NBKT];
  const int t = threadIdx.x;
  for (int k = t; k < NBKT; k += 256) h[k] = 0;
  __syncthreads();
  const int base = blockIdx.x * E_PER_BLK;
  for (int i = t; i < E_PER_BLK; i += 256) atomicAdd(&h[dst[base + i] >> 8], 1);
  __syncthreads();
  for (int k = t; k < NBKT; k += 256) cnt[k * F_BLOCKS + blockIdx.x] = h[k];
}

// ---- generic hierarchical exclusive scan (block prefix applied at use site) ----
__global__ __launch_bounds__(256) void scan1g_kernel(const int* __restrict__ in,
                                                     int* __restrict__ ex,
                                                     int* __restrict__ bsum, int n) {
  __shared__ int s[256];
  const int t = threadIdx.x;
  const int i = blockIdx.x * 256 + t;
  int v = (i < n) ? in[i] : 0;
  s[t] = v;
  __syncthreads();
#pragma unroll
  for (int ofs = 1; ofs < 256; ofs <<= 1) {
    int u = (t >= ofs) ? s[t - ofs] : 0;
    __syncthreads();
    s[t] += u;
    __syncthreads();
  }
  if (i < n) ex[i] = s[t] - v;
  if (t == 255) bsum[blockIdx.x] = s[255];
}

__global__ __launch_bounds__(256) void scan2g_kernel(const int* __restrict__ bsum,
                                                     int* __restrict__ bpref, int nb) {
  __shared__ int s[256];
  const int t = threadIdx.x;
  int v = (t < nb) ? bsum[t] : 0;
  s[t] = v;
  __syncthreads();
#pragma unroll
  for (int ofs = 1; ofs < 256; ofs <<= 1) {
    int u = (t >= ofs) ? s[t - ofs] : 0;
    __syncthreads();
    s[t] += u;
    __syncthreads();
  }
  if (t < nb) bpref[t] = s[t] - v;
}

// ---- F3: partition edges into coarse-bucket order (LDS cursors; bpref applied inline) ----
__global__ __launch_bounds__(256) void part_scatter_kernel(const int* __restrict__ src,
                                                           const int* __restrict__ dst,
                                                           const int* __restrict__ cex,
                                                           const int* __restrict__ bpref,
                                                           int* __restrict__ psrc,
                                                           int* __restrict__ pdst) {
  __shared__ int cur[NBKT];
  const int t = threadIdx.x;
  for (int k = t; k < NBKT; k += 256) {
    const int i = k * F_BLOCKS + blockIdx.x;
    cur[k] = cex[i] + bpref[i >> 8];
  }
  __syncthreads();
  const int base = blockIdx.x * E_PER_BLK;
  for (int i = t; i < E_PER_BLK; i += 256) {
    int d = dst[base + i], s = src[base + i];
    int p = atomicAdd(&cur[d >> 8], 1);
    pdst[p] = d;
    psrc[p] = s;
  }
}

// ---- F4: per-bucket counting sort -> csr + off; degree histogram folded in ----
__global__ __launch_bounds__(256) void bucket_sort_kernel(const int* __restrict__ psrc,
                                                          const int* __restrict__ pdst,
                                                          const int* __restrict__ cex,
                                                          const int* __restrict__ bpref,
                                                          int* __restrict__ csr,
                                                          int* __restrict__ off,
                                                          int* __restrict__ dcnt) {
  const int k = blockIdx.x;
  const int t = threadIdx.x;
  const int i0 = k * F_BLOCKS;
  const int b0 = cex[i0] + bpref[i0 >> 8];
  int b1 = N_EDGES;
  if (k != NBKT - 1) {
    const int i1 = (k + 1) * F_BLOCKS;
    b1 = cex[i1] + bpref[i1 >> 8];
  }
  __shared__ int cnt[256];
  __shared__ int s[256];
  __shared__ int cur[256];
  __shared__ int dhist[64];
  cnt[t] = 0;
  if (t < 64) dhist[t] = 0;
  __syncthreads();
  for (int i = b0 + t; i < b1; i += 256) atomicAdd(&cnt[pdst[i] & 255], 1);
  __syncthreads();
  int v = cnt[t];
  s[t] = v;
  __syncthreads();
#pragma unroll
  for (int ofs = 1; ofs < 256; ofs <<= 1) {
    int u = (t >= ofs) ? s[t - ofs] : 0;
    __syncthreads();
    s[t] += u;
    __syncthreads();
  }
  const int node = (k << 8) + t;
  const int start = b0 + s[t] - v;
  cur[t] = start;
  if (node < N_NODES) {
    off[node] = start;
    atomicAdd(&dhist[(v < 63) ? v : 63], 1);
  }
  if (k == NBKT - 1 && t == 0) off[N_NODES] = N_EDGES;
  __syncthreads();
  if (t < 64) dcnt[t * NBKT + k] = dhist[t];
  for (int i = b0 + t; i < b1; i += 256) {
    int d = pdst[i];
    int p = atomicAdd(&cur[d & 255], 1);
    csr[p] = psrc[i];
  }
}

// ---- F5: scatter nodes into degree-sorted permutation ----
__global__ __launch_bounds__(256) void perm_scatter_kernel(const int* __restrict__ off,
                                                           const int* __restrict__ dex,
                                                           const int* __restrict__ dbpref,
                                                           int* __restrict__ perm) {
  __shared__ int cur[64];
  const int k = blockIdx.x, t = threadIdx.x;
  if (t < 64) {
    const int i = t * NBKT + k;
    cur[t] = dex[i] + dbpref[i >> 8];
  }
  __syncthreads();
  const int node = (k << 8) + t;
  if (node < N_NODES) {
    int d = off[node + 1] - off[node];
    d = (d < 63) ? d : 63;
    int pos = atomicAdd(&cur[d], 1);
    perm[pos] = node;
  }
}

// ---- proj (MFMA): h = relu(x @ Wp + bp), one wave per 16-node tile, K=128 ----
// Wp fragment order: frag f = nc*4+ks (nc=j>>4, ks=k>>5), lane=((k>>3)&3)*16+(j&15),
// elem=k&7. A: lane(row,kgrp) holds x[n0+row][ks*32+kgrp*8 .. +8) as bf16.
// C/D: col=lane&15, row=(lane>>4)*4+reg (verified r13).
__global__ __launch_bounds__(256) void proj_mfma_kernel(
    const float* __restrict__ x, const float* __restrict__ Wp,
    const float* __restrict__ bp, unsigned short* __restrict__ h) {
  __shared__ __align__(16) unsigned short sWp[8192];     // 16 KB, fragment-ordered
  __shared__ __align__(16) unsigned short sT[4][16][72]; // 9 KB transpose
  const int t = threadIdx.x;
  for (int i = t; i < 8192; i += 256) {
    const int k = i >> 6, j = i & 63;
    const int pos = (((j >> 4) * 4 + (k >> 5)) * 64 + ((k >> 3) & 3) * 16 + (j & 15)) * 8 + (k & 7);
    sWp[pos] = f2bf(Wp[i]);
  }
  __syncthreads();
  const int wave = t >> 6, lane = t & 63;
  const int row = lane & 15;
  const int kgrp = lane >> 4;
  float bias[4];
#pragma unroll
  for (int nc = 0; nc < 4; ++nc) bias[nc] = bp[nc * 16 + row];
  const int tile = blockIdx.x * 4 + wave;
  if (tile < MTILES) {
    const int n = tile * 16 + row;
    bf16x8 a[4];
#pragma unroll
    for (int ks = 0; ks < 4; ++ks) {
      float4 v0 = *(const float4*)&x[n * IN_DIM + ks * 32 + kgrp * 8];
      float4 v1 = *(const float4*)&x[n * IN_DIM + ks * 32 + kgrp * 8 + 4];
      a[ks][0] = (short)f2bf(v0.x);
      a[ks][1] = (short)f2bf(v0.y);
      a[ks][2] = (short)f2bf(v0.z);
      a[ks][3] = (short)f2bf(v0.w);
      a[ks][4] = (short)f2bf(v1.x);
      a[ks][5] = (short)f2bf(v1.y);
      a[ks][6] = (short)f2bf(v1.z);
      a[ks][7] = (short)f2bf(v1.w);
    }
    f32x4 acc;
#pragma unroll
    for (int nc = 0; nc < 4; ++nc) {
      acc = (f32x4){bias[nc], bias[nc], bias[nc], bias[nc]};
#pragma unroll
      for (int ks = 0; ks < 4; ++ks) {
        bf16x8 bf = *(const bf16x8*)&sWp[((nc * 4 + ks) * 64 + lane) * 8];
        acc = __builtin_amdgcn_mfma_f32_16x16x32_bf16(a[ks], bf, acc, 0, 0, 0);
      }
#pragma unroll
      for (int r = 0; r < 4; ++r)
        sT[wave][kgrp * 4 + r][nc * 16 + row] = f2bf(fmaxf(acc[r], 0.0f));
    }
    const int n0 = tile * 16;
#pragma unroll
    for (int p = 0; p < 2; ++p) {
      const int idx2 = p * 64 + lane;
      const int ri = idx2 >> 3, ch = idx2 & 7;
      uint4 v = *(const uint4*)&sT[wave][ri][ch * 8];
      *(uint4*)&h[(n0 + ri) * HID + ch * 8] = v;
    }
  }
}

// ---- fused GIN layer (MFMA, degree-sorted tiles, r15-exact) ----
__global__ __launch_bounds__(256) void gin_fused_mfma_kernel(
    const unsigned short* __restrict__ h_in, const int* __restrict__ off,
    const int* __restrict__ csr, const int* __restrict__ perm,
    const float* __restrict__ W1, const float* __restrict__ b1,
    const float* __restrict__ W2, const float* __restrict__ b2,
    unsigned short* __restrict__ h_out) {
  __shared__ __align__(16) unsigned short sW1[4096];     // 8 KB, fragment-ordered
  __shared__ __align__(16) unsigned short sW2[4096];     // 8 KB
  __shared__ __align__(16) unsigned short sT[4][16][72]; // per-wave transpose, pad->144B rows
  const int t = threadIdx.x;
  for (int i = t; i < 4096; i += 256) {
    const int k = i >> 6, j = i & 63;
    const int pos = (((j >> 4) * 2 + (k >> 5)) * 64 + ((k >> 3) & 3) * 16 + (j & 15)) * 8 + (k & 7);
    sW1[pos] = f2bf(W1[i]);
    sW2[pos] = f2bf(W2[i]);
  }
  __syncthreads();
  const int wave = t >> 6, lane = t & 63;
  const int row = lane & 15;   // A-row / D-col
  const int kgrp = lane >> 4;  // 0..3
  float bias1[4], bias2[4];
#pragma unroll
  for (int nc = 0; nc < 4; ++nc) {
    bias1[nc] = b1[nc * 16 + row];
    bias2[nc] = b2[nc * 16 + row];
  }
  const uint4* __restrict__ hv = (const uint4*)h_in;  // 8 x 16B segments per row
  const int tile = blockIdx.x * 4 + wave;
  if (tile < MTILES) {
    const int n = perm[(tile << 4) + row];  // degree-sorted node for this row
    const int o0 = off[n];
    const int deg = off[n + 1] - o0;
    // wave-max degree (~= mean after sorting)
    int dm = deg;
#pragma unroll
    for (int m = 1; m <= 8; m <<= 1) {
      int o = __shfl_xor(dm, m);
      dm = (o > dm) ? o : dm;
    }
    // self term
    float ac0[8], ac1[8];
    {
      uint4 ua = hv[n * 8 + kgrp];
      uint4 ub = hv[n * 8 + 4 + kgrp];
      const unsigned int* pa = (const unsigned int*)&ua;
      const unsigned int* pb = (const unsigned int*)&ub;
#pragma unroll
      for (int e = 0; e < 4; ++e) {
        ac0[2 * e] = bf2f((unsigned short)(pa[e] & 0xffff));
        ac0[2 * e + 1] = bf2f((unsigned short)(pa[e] >> 16));
        ac1[2 * e] = bf2f((unsigned short)(pb[e] & 0xffff));
        ac1[2 * e + 1] = bf2f((unsigned short)(pb[e] >> 16));
      }
    }
    // neighbors: branchless, 4-way unrolled (waste ~ (dm-deg)/dm, small after sorting)
    for (int j = 0; j < dm; j += 4) {
#pragma unroll
      for (int u = 0; u < 4; ++u) {
        const int jj = j + u;
        const int pos = o0 + ((jj < deg) ? jj : 0);
        const int idx = csr[(pos < N_EDGES) ? pos : (N_EDGES - 1)];
        const float m = (jj < deg) ? 1.0f : 0.0f;
        uint4 ua = hv[idx * 8 + kgrp];
        uint4 ub = hv[idx * 8 + 4 + kgrp];
        const unsigned int* pa = (const unsigned int*)&ua;
        const unsigned int* pb = (const unsigned int*)&ub;
#pragma unroll
        for (int e = 0; e < 4; ++e) {
          ac0[2 * e] = fmaf(m, bf2f((unsigned short)(pa[e] & 0xffff)), ac0[2 * e]);
          ac0[2 * e + 1] = fmaf(m, bf2f((unsigned short)(pa[e] >> 16)), ac0[2 * e + 1]);
          ac1[2 * e] = fmaf(m, bf2f((unsigned short)(pb[e] & 0xffff)), ac1[2 * e]);
          ac1[2 * e + 1] = fmaf(m, bf2f((unsigned short)(pb[e] >> 16)), ac1[2 * e + 1]);
        }
      }
    }
    // pack A-fragments
    bf16x8 a1[2];
#pragma unroll
    for (int e = 0; e < 8; ++e) {
      a1[0][e] = (short)f2bf(ac0[e]);
      a1[1][e] = (short)f2bf(ac1[e]);
    }
    f32x4 acc;
#pragma unroll
    for (int nc = 0; nc < 4; ++nc) {
      acc = (f32x4){bias1[nc], bias1[nc], bias1[nc], bias1[nc]};
#pragma unroll
      for (int ks = 0; ks < 2; ++ks) {
        bf16x8 bf = *(const bf16x8*)&sW1[((nc * 2 + ks) * 64 + lane) * 8];
        acc = __builtin_amdgcn_mfma_f32_16x16x32_bf16(a1[ks], bf, acc, 0, 0, 0);
      }
#pragma unroll
      for (int r = 0; r < 4; ++r)
        sT[wave][kgrp * 4 + r][nc * 16 + row] = f2bf(fmaxf(acc[r], 0.0f));
    }
    bf16x8 a2[2];
    a2[0] = *(const bf16x8*)&sT[wave][row][kgrp * 8];
    a2[1] = *(const bf16x8*)&sT[wave][row][32 + kgrp * 8];
#pragma unroll
    for (int nc = 0; nc < 4; ++nc) {
      acc = (f32x4){bias2[nc], bias2[nc], bias2[nc], bias2[nc]};
#pragma unroll
      for (int ks = 0; ks < 2; ++ks) {
        bf16x8 bf = *(const bf16x8*)&sW2[((nc * 2 + ks) * 64 + lane) * 8];
        acc = __builtin_amdgcn_mfma_f32_16x16x32_bf16(a2[ks], bf, acc, 0, 0, 0);
      }
#pragma unroll
      for (int r = 0; r < 4; ++r)
        sT[wave][kgrp * 4 + r][nc * 16 + row] = f2bf(fmaxf(acc[r], 0.0f));
    }
    // store: 16 rows x 64 bf16 via uint4; rows go to permuted node positions
#pragma unroll
    for (int p = 0; p < 2; ++p) {
      const int idx2 = p * 64 + lane;
      const int ri = idx2 >> 3, ch = idx2 & 7;
      const int nodeo = perm[(tile << 4) + ri];  // L1-hot reload
      uint4 v = *(const uint4*)&sT[wave][ri][ch * 8];
      *(uint4*)&h_out[nodeo * HID + ch * 8] = v;
    }
  }
}

// ------- pool: batch sorted -> one block per graph, binary-search range -------
__global__ __launch_bounds__(256) void pool_kernel(const unsigned short* __restrict__ h,
                                                   const int* __restrict__ batch,
                                                   float* __restrict__ out) {
  const int g = blockIdx.x;
  int lo = 0, hi = N_NODES;
  while (lo < hi) {
    int mid = (lo + hi) >> 1;
    if (batch[mid] < g) lo = mid + 1; else hi = mid;
  }
  const int s = lo;
  hi = N_NODES;
  while (lo < hi) {
    int mid = (lo + hi) >> 1;
    if (batch[mid] < g + 1) lo = mid + 1; else hi = mid;
  }
  const int e = lo;
  const int wave = threadIdx.x >> 6, lane = threadIdx.x & 63;
  float a0 = 0.f, a1 = 0.f, a2 = 0.f, a3 = 0.f;
  int n = s + wave;
  for (; n + 12 < e; n += 16) {
    a0 += bf2f(h[n * HID + lane]);
    a1 += bf2f(h[(n + 4) * HID + lane]);
    a2 += bf2f(h[(n + 8) * HID + lane]);
    a3 += bf2f(h[(n + 12) * HID + lane]);
  }
  for (; n < e; n += 4) a0 += bf2f(h[n * HID + lane]);
  __shared__ float red[4][HID];
  red[wave][lane] = ((a0 + a1) + (a2 + a3));
  __syncthreads();
  if (wave == 0) {
    float v = red[0][lane] + red[1][lane] + red[2][lane] + red[3][lane];
    float cnt = (float)(e - s);
    out[g * HID + lane] = v / fmaxf(cnt, 1.0f);
  }
}

extern "C" void kernel_launch(void* const* d_in, const int* in_sizes, int n_in,
                              void* d_out, int out_size, void* d_ws, size_t ws_size,
                              hipStream_t stream) {
  const float* x    = (const float*)d_in[0];
  const int*   edge = (const int*)d_in[1];
  const int*   batch= (const int*)d_in[2];
  const float* Wp   = (const float*)d_in[3];
  const float* bp   = (const float*)d_in[4];
  const float* W1_0 = (const float*)d_in[5];
  const float* b1_0 = (const float*)d_in[6];
  const float* W2_0 = (const float*)d_in[7];
  const float* b2_0 = (const float*)d_in[8];
  const float* W1_1 = (const float*)d_in[9];
  const float* b1_1 = (const float*)d_in[10];
  const float* W2_1 = (const float*)d_in[11];
  const float* b2_1 = (const float*)d_in[12];
  const int* src = edge;
  const int* dst = edge + N_EDGES;
  float* out = (float*)d_out;

  const size_t NB = (size_t)N_NODES * HID;
  unsigned short* hA = (unsigned short*)d_ws;  // NB bf16
  unsigned short* hB = hA + NB;                // NB bf16
  int* off     = (int*)(hB + NB);   // N_NODES+1
  int* cnt     = off + N_NODES + 1; // CNT_N
  int* cex     = cnt + CNT_N;       // CNT_N
  int* sbsum   = cex + CNT_N;       // SCB
  int* sbpref  = sbsum + SCB;       // SCB
  int* dcnt    = sbpref + SCB;      // DCNT_N
  int* dex     = dcnt + DCNT_N;     // DCNT_N
  int* dbsum   = dex + DCNT_N;      // DSCB
  int* dbpref  = dbsum + DSCB;      // DSCB
  int* perm    = dbpref + DSCB;     // N_NODES
  int* pdst    = perm + N_NODES;    // N_EDGES
  int* psrc    = pdst + N_EDGES;    // N_EDGES
  int* csr     = psrc + N_EDGES;    // N_EDGES

  dim3 b256(256);

  // CSR build: counting sort, zero global atomics
  part_hist_kernel<<<F_BLOCKS, b256, 0, stream>>>(dst, cnt);
  scan1g_kernel<<<SCB, b256, 0, stream>>>(cnt, cex, sbsum, CNT_N);
  scan2g_kernel<<<1, b256, 0, stream>>>(sbsum, sbpref, SCB);
  part_scatter_kernel<<<F_BLOCKS, b256, 0, stream>>>(src, dst, cex, sbpref, psrc, pdst);
  bucket_sort_kernel<<<NBKT, b256, 0, stream>>>(psrc, pdst, cex, sbpref, csr, off, dcnt);

  // degree-sorted permutation
  scan1g_kernel<<<DSCB, b256, 0, stream>>>(dcnt, dex, dbsum, DCNT_N);
  scan2g_kernel<<<1, b256, 0, stream>>>(dbsum, dbpref, DSCB);
  perm_scatter_kernel<<<NBKT, b256, 0, stream>>>(off, dex, dbpref, perm);

  // h0 -> hA (MFMA proj)
  proj_mfma_kernel<<<782, b256, 0, stream>>>(x, Wp, bp, hA);

  // fused layers: hA -> hB -> hA  (782 blocks x 4 waves = 3128 tiles >= 3125)
  gin_fused_mfma_kernel<<<782, b256, 0, stream>>>(hA, off, csr, perm, W1_0, b1_0, W2_0, b2_0, hB);
  gin_fused_mfma_kernel<<<782, b256, 0, stream>>>(hB, off, csr, perm, W1_1, b1_1, W2_1, b2_1, hA);

  // pool
  pool_kernel<<<N_GRAPHS, b256, 0, stream>>>(hA, batch, out);
}